// Round 2
// baseline (134.619 us; speedup 1.0000x reference)
//
#include <hip/hip_runtime.h>

// Complex magnitude max-pool 2x2 (stride 2, VALID), NHWC.
// Input: x_real, x_imag [8,512,512,32] f32. Output: [8,256,256,32,2] f32.
// Identity: mag*cos(atan2(im,re)) == re, mag*sin(...) == im, so the op is an
// argmax(|x|)-gather of (re,im) over each 2x2 window.
// CRITICAL: the argmax key must be computed bit-exactly like the reference
// (separately rounded mul/mul/add, IEEE sqrt) so tie/near-tie windows resolve
// to the same element. Strict '>' = first-occurrence wins, like jnp.argmax.

constexpr int B  = 8;
constexpr int H  = 512;
constexpr int W  = 512;
constexpr int C  = 32;
constexpr int Ho = H / 2;
constexpr int Wo = W / 2;
// Each work-item handles 4 consecutive channels (one float4 lane group).
constexpr long TOTAL = (long)B * Ho * Wo * (C / 4);

__device__ __forceinline__ float ref_mag(float r, float i) {
  // Match numpy: each op individually rounded, correctly-rounded sqrt,
  // no fma contraction.
  return __fsqrt_rn(__fadd_rn(__fmul_rn(r, r), __fmul_rn(i, i)));
}

__global__ __launch_bounds__(256) void cmaxpool_kernel(
    const float* __restrict__ xr,
    const float* __restrict__ xi,
    float* __restrict__ out) {
  const long stride = (long)gridDim.x * blockDim.x;
  for (long g = (long)blockIdx.x * blockDim.x + threadIdx.x; g < TOTAL; g += stride) {
    const int c4 = (int)(g & 7);          // C/4 = 8 channel groups
    long t = g >> 3;
    const int wo = (int)(t & (Wo - 1));   t >>= 8;
    const int ho = (int)(t & (Ho - 1));   t >>= 8;
    const int b  = (int)t;
    const int c  = c4 * 4;

    const long ibase = ((((long)b * H + 2 * ho) * W) + 2 * wo) * C + c;
    const long rowstep = (long)W * C;     // h+1

    // 4 window positions in jnp.argmax order: (0,0),(0,1),(1,0),(1,1)
    float4 R[4], I[4];
    R[0] = *(const float4*)(xr + ibase);
    R[1] = *(const float4*)(xr + ibase + C);
    R[2] = *(const float4*)(xr + ibase + rowstep);
    R[3] = *(const float4*)(xr + ibase + rowstep + C);
    I[0] = *(const float4*)(xi + ibase);
    I[1] = *(const float4*)(xi + ibase + C);
    I[2] = *(const float4*)(xi + ibase + rowstep);
    I[3] = *(const float4*)(xi + ibase + rowstep + C);

    float ore[4], oim[4];
#pragma unroll
    for (int j = 0; j < 4; ++j) {
      float br = ((const float*)&R[0])[j];
      float bi = ((const float*)&I[0])[j];
      float bm = ref_mag(br, bi);
#pragma unroll
      for (int k = 1; k < 4; ++k) {
        const float rr = ((const float*)&R[k])[j];
        const float ii = ((const float*)&I[k])[j];
        const float m  = ref_mag(rr, ii);
        if (m > bm) { bm = m; br = rr; bi = ii; }   // strict > == first-wins
      }
      ore[j] = br;
      oim[j] = bi;
    }

    // Output layout [B,Ho,Wo,C,2]; base is 32B-aligned (c % 4 == 0).
    const long obase = ((((long)b * Ho + ho) * Wo + wo) * C + c) * 2;
    float4 o0, o1;
    o0.x = ore[0]; o0.y = oim[0]; o0.z = ore[1]; o0.w = oim[1];
    o1.x = ore[2]; o1.y = oim[2]; o1.z = ore[3]; o1.w = oim[3];
    *(float4*)(out + obase)     = o0;
    *(float4*)(out + obase + 4) = o1;
  }
}

extern "C" void kernel_launch(void* const* d_in, const int* in_sizes, int n_in,
                              void* d_out, int out_size, void* d_ws, size_t ws_size,
                              hipStream_t stream) {
  const float* xr = (const float*)d_in[0];
  const float* xi = (const float*)d_in[1];
  float* out = (float*)d_out;

  const int block = 256;
  int grid = (int)((TOTAL + block - 1) / block);
  if (grid > 2048) grid = 2048;   // grid-stride the rest (memory-bound, G11)
  cmaxpool_kernel<<<grid, block, 0, stream>>>(xr, xi, out);
}